// Round 1
// baseline (146.475 us; speedup 1.0000x reference)
//
#include <hip/hip_runtime.h>

typedef unsigned short u16;
typedef __attribute__((ext_vector_type(4))) float f32x4;
typedef __attribute__((ext_vector_type(8))) short s16x8;

static constexpr int N_ = 4096;
static constexpr int D_ = 1024;

__device__ __forceinline__ u16 f2bf(float f) {
  unsigned u = __float_as_uint(f);
  u += 0x7FFFu + ((u >> 16) & 1u);   // RNE
  return (u16)(u >> 16);
}

__device__ __forceinline__ f32x4 zero4() {
  f32x4 z; z[0] = 0.f; z[1] = 0.f; z[2] = 0.f; z[3] = 0.f; return z;
}

// ---------------- K0: W_sum + bf16 pre-conversion ----------------
__global__ __launch_bounds__(256) void k_prep(
    const float* __restrict__ Wpm, const float* __restrict__ piw,
    const float* __restrict__ pw, u16* __restrict__ WpB,
    u16* __restrict__ PowB, u16* __restrict__ WsumB) {
  int bid = blockIdx.x, tid = threadIdx.x;
  if (bid < 8) {
    for (int idx = tid; idx < 4096; idx += 256) {
      float s = 0.f;
#pragma unroll
      for (int k = 0; k < 8; ++k)
        s += Wpm[((size_t)(bid * 8 + k)) * 4096 + idx];
      WsumB[bid * 4096 + idx] = f2bf(s);
    }
  } else if (bid < 24) {
    size_t i0 = (size_t)(bid - 8) * 4096;
    for (int idx = tid; idx < 4096; idx += 256)
      WpB[i0 + idx] = f2bf(piw[i0 + idx]);
  } else {
    size_t i0 = (size_t)(bid - 24) * 4096;
    for (int idx = tid; idx < 4096; idx += 256)
      PowB[i0 + idx] = f2bf(pw[i0 + idx]);
  }
}

// ---------------- K1: fused read/commit main pass ----------------
// grid = 8 batches * 64 row-tiles, 256 threads (4 waves), 64 rows/block.
__global__ __launch_bounds__(256) void k_main(
    const float* __restrict__ H, const float* __restrict__ Sur,
    const float* __restrict__ pib, const float* __restrict__ pob,
    const float* __restrict__ sscale_p, const float* __restrict__ sbias_p,
    const u16* __restrict__ WpB, const u16* __restrict__ PowB,
    const u16* __restrict__ WsumB, float* __restrict__ Gacc,
    float* __restrict__ out) {
  __shared__ u16 preRP[64][72];   // pre (with bias), bf16, [row][p], pad 72
  __shared__ u16 wRP[64][72];     // sqrt(s)*pre
  __shared__ u16 postRP[64][72];  // post
  __shared__ float sqs[64];

  const int tid = threadIdx.x;
  const int lane = tid & 63;
  const int w = tid >> 6;         // wave 0..3 -> rows w*16..w*16+15
  const int llo = lane & 15;
  const int lhi = lane >> 4;
  const int b = blockIdx.x >> 6;
  const int row0 = (blockIdx.x & 63) * 64;

  const float sscale = sscale_p[0];
  const float sbias = sbias_p[0];

  // ---- surprise row norms -> sqrt(sigmoid(scale*mag+bias)) ----
  {
    const float* sbase = Sur + ((size_t)b * N_ + row0) * D_;
    for (int i = 0; i < 16; ++i) {
      int r = w * 16 + i;
      const float* p = sbase + (size_t)r * D_ + lane * 4;
      float a = 0.f;
#pragma unroll
      for (int j = 0; j < 4; ++j) {
        float4 v = *(const float4*)(p + j * 256);
        a += v.x * v.x + v.y * v.y + v.z * v.z + v.w * v.w;
      }
#pragma unroll
      for (int m = 1; m < 64; m <<= 1) a += __shfl_xor(a, m, 64);
      if (lane == 0) {
        float mag = sqrtf(a);
        float s = 1.f / (1.f + __expf(-(sscale * mag + sbias)));
        sqs[r] = sqrtf(s);
      }
    }
  }
  __syncthreads();

  // ---- phase A: pre[64][64] = H_rows @ Wp^T  (K=1024, bf16 MFMA) ----
  f32x4 accA[4];
#pragma unroll
  for (int t = 0; t < 4; ++t) accA[t] = zero4();
  {
    const float* hrow =
        H + ((size_t)b * N_ + row0 + w * 16 + llo) * D_ + lhi * 8;
    const u16* wp0 = WpB + (size_t)llo * 1024 + lhi * 8;
#pragma unroll 2
    for (int k0 = 0; k0 < 1024; k0 += 32) {
      float4 a0 = *(const float4*)(hrow + k0);
      float4 a1 = *(const float4*)(hrow + k0 + 4);
      s16x8 af;
      af[0] = (short)f2bf(a0.x); af[1] = (short)f2bf(a0.y);
      af[2] = (short)f2bf(a0.z); af[3] = (short)f2bf(a0.w);
      af[4] = (short)f2bf(a1.x); af[5] = (short)f2bf(a1.y);
      af[6] = (short)f2bf(a1.z); af[7] = (short)f2bf(a1.w);
#pragma unroll
      for (int t = 0; t < 4; ++t) {
        s16x8 bf = *(const s16x8*)(wp0 + (size_t)t * 16 * 1024 + k0);
        accA[t] = __builtin_amdgcn_mfma_f32_16x16x32_bf16(af, bf, accA[t], 0, 0, 0);
      }
    }
  }
#pragma unroll
  for (int t = 0; t < 4; ++t) {
    float bias = pib[t * 16 + llo];
#pragma unroll
    for (int r = 0; r < 4; ++r) {
      int rr = w * 16 + lhi * 4 + r;
      float v = accA[t][r] + bias;
      preRP[rr][t * 16 + llo] = f2bf(v);
      wRP[rr][t * 16 + llo] = f2bf(v * sqs[rr]);
    }
  }
  __syncthreads();

  // ---- phase G: G += weighted^T @ weighted (K=64 rows) ----
  {
    f32x4 accG[4];
#pragma unroll
    for (int t = 0; t < 4; ++t) accG[t] = zero4();
#pragma unroll
    for (int k0 = 0; k0 < 64; k0 += 32) {
      s16x8 ag;
#pragma unroll
      for (int j = 0; j < 8; ++j)
        ag[j] = (short)wRP[k0 + lhi * 8 + j][w * 16 + llo];
#pragma unroll
      for (int t = 0; t < 4; ++t) {
        s16x8 bg;
#pragma unroll
        for (int j = 0; j < 8; ++j)
          bg[j] = (short)wRP[k0 + lhi * 8 + j][t * 16 + llo];
        accG[t] = __builtin_amdgcn_mfma_f32_16x16x32_bf16(ag, bg, accG[t], 0, 0, 0);
      }
    }
    float* gb = Gacc + (size_t)b * 4096;
#pragma unroll
    for (int t = 0; t < 4; ++t)
#pragma unroll
      for (int r = 0; r < 4; ++r)
        atomicAdd(gb + (w * 16 + lhi * 4 + r) * 64 + t * 16 + llo, accG[t][r]);
  }

  // ---- phase C: post = pre @ W_sum^T (K=64) ----
  {
    f32x4 accC[4];
#pragma unroll
    for (int t = 0; t < 4; ++t) accC[t] = zero4();
    const u16* wsb = WsumB + (size_t)b * 4096;
#pragma unroll
    for (int k0 = 0; k0 < 64; k0 += 32) {
      s16x8 ac = *(const s16x8*)&preRP[w * 16 + llo][k0 + lhi * 8];
#pragma unroll
      for (int t = 0; t < 4; ++t) {
        s16x8 bc = *(const s16x8*)(wsb + (size_t)(t * 16 + llo) * 64 + k0 + lhi * 8);
        accC[t] = __builtin_amdgcn_mfma_f32_16x16x32_bf16(ac, bc, accC[t], 0, 0, 0);
      }
    }
#pragma unroll
    for (int t = 0; t < 4; ++t)
#pragma unroll
      for (int r = 0; r < 4; ++r)
        postRP[w * 16 + lhi * 4 + r][t * 16 + llo] = f2bf(accC[t][r]);
  }
  __syncthreads();

  // ---- phase D: pm_read = post @ Pow^T + bias (N=1024) ----
  {
    s16x8 ad0 = *(const s16x8*)&postRP[w * 16 + llo][lhi * 8];
    s16x8 ad1 = *(const s16x8*)&postRP[w * 16 + llo][32 + lhi * 8];
    float* orow = out + ((size_t)b * N_ + row0 + w * 16) * D_;
    for (int n0 = 0; n0 < 1024; n0 += 16) {
      s16x8 b0 = *(const s16x8*)(PowB + (size_t)(n0 + llo) * 64 + lhi * 8);
      s16x8 b1 = *(const s16x8*)(PowB + (size_t)(n0 + llo) * 64 + 32 + lhi * 8);
      f32x4 acc = zero4();
      acc = __builtin_amdgcn_mfma_f32_16x16x32_bf16(ad0, b0, acc, 0, 0, 0);
      acc = __builtin_amdgcn_mfma_f32_16x16x32_bf16(ad1, b1, acc, 0, 0, 0);
      float bias = pob[n0 + llo];
#pragma unroll
      for (int r = 0; r < 4; ++r)
        orow[(size_t)(lhi * 4 + r) * D_ + n0 + llo] = acc[r] + bias;
    }
  }
}

// ---------------- K2: W_new = W_pm @ (decay*I + beta*G/N), frob clip ----------------
__global__ __launch_bounds__(256) void k_wnew(
    const float* __restrict__ Wpm, const float* __restrict__ Gacc,
    const float* __restrict__ rbeta, const float* __restrict__ rdecay,
    float* __restrict__ outW) {
  __shared__ float Wk[64][66];
  __shared__ float Gl[64][66];
  __shared__ float red[4];
  int bk = blockIdx.x;
  int b = bk >> 3, k = bk & 7;
  int tid = threadIdx.x;
  const float* wsrc = Wpm + (size_t)bk * 4096;
  const float* gsrc = Gacc + (size_t)b * 4096;
  for (int idx = tid; idx < 4096; idx += 256) {
    Wk[idx >> 6][idx & 63] = wsrc[idx];
    Gl[idx >> 6][idx & 63] = gsrc[idx];
  }
  __syncthreads();
  float beta = log1pf(__expf(rbeta[k]));
  float decay = 1.f / (1.f + __expf(-rdecay[k]));
  float bn = beta * (1.f / 4096.f);  // beta/N (G was accumulated unnormalized)
  int q = tid & 63;
  int rbase = tid >> 6;
  float vals[16];
  float ss = 0.f;
#pragma unroll
  for (int i = 0; i < 16; ++i) {
    int row = i * 4 + rbase;
    float acc = 0.f;
#pragma unroll 8
    for (int j = 0; j < 64; ++j) acc += Wk[row][j] * Gl[j][q];
    float v = decay * Wk[row][q] + bn * acc;
    vals[i] = v;
    ss += v * v;
  }
#pragma unroll
  for (int m = 1; m < 64; m <<= 1) ss += __shfl_xor(ss, m, 64);
  if ((tid & 63) == 0) red[tid >> 6] = ss;
  __syncthreads();
  float frob = sqrtf(red[0] + red[1] + red[2] + red[3]);
  float scale = fminf(16.f / fmaxf(frob, 1e-8f), 1.f);
  float* dst = outW + (size_t)bk * 4096;
#pragma unroll
  for (int i = 0; i < 16; ++i) dst[i * 256 + tid] = vals[i] * scale;
}

extern "C" void kernel_launch(void* const* d_in, const int* in_sizes, int n_in,
                              void* d_out, int out_size, void* d_ws, size_t ws_size,
                              hipStream_t stream) {
  const float* H      = (const float*)d_in[0];
  const float* Sur    = (const float*)d_in[1];
  const float* Wpm    = (const float*)d_in[2];
  const float* piw    = (const float*)d_in[3];
  const float* pib    = (const float*)d_in[4];
  const float* pw     = (const float*)d_in[5];
  const float* pob    = (const float*)d_in[6];
  const float* rbeta  = (const float*)d_in[7];
  const float* rdecay = (const float*)d_in[8];
  const float* sscale = (const float*)d_in[9];
  const float* sbias  = (const float*)d_in[10];
  float* out = (float*)d_out;

  char* ws = (char*)d_ws;
  float* Gacc = (float*)(ws);                 // [8][64][64] f32 = 131072 B
  u16* WsumB  = (u16*)(ws + 131072);          // [8][64][64] bf16 = 65536 B
  u16* WpB    = (u16*)(ws + 196608);          // [64][1024] bf16 = 131072 B
  u16* PowB   = (u16*)(ws + 327680);          // [1024][64] bf16 = 131072 B

  hipMemsetAsync(Gacc, 0, 131072, stream);
  k_prep<<<40, 256, 0, stream>>>(Wpm, piw, pw, WpB, PowB, WsumB);
  k_main<<<512, 256, 0, stream>>>(H, Sur, pib, pob, sscale, sbias,
                                  WpB, PowB, WsumB, Gacc, out);
  k_wnew<<<64, 256, 0, stream>>>(Wpm, Gacc, rbeta, rdecay,
                                 out + (size_t)8 * 4096 * 1024);
}